// Round 10
// baseline (61.093 us; speedup 1.0000x reference)
//
#include <hip/hip_runtime.h>

#define EPS 1e-8f

// Shapes fixed per reference: x [B=8, N=8192, D=512] fp32, scalar fp32 out.
#define B_DIM 8
#define N_DIM 8192
#define D_DIM 512
#define CHUNKS 128   // real K1: grid = B*CHUNKS = 1024 blocks (4/CU, 16 waves/CU)
#define FIX_SCALE 1099511627776.0   // 2^40 fixed-point scale for deterministic sum

typedef float fx4 __attribute__((ext_vector_type(4)));

// K1 (templated on chunk count for the A/B probe): 256 threads (4 waves).
// Each wave: rowsPerWave rows, 4 rows/iteration, register double-buffer.
// Lane l owns d-slice [8l, 8l+8). If acc!=null, block 0 zeroes acc/ticket.
template <int CHUNKS_T>
__global__ __launch_bounds__(256) void k1_partial(const float* __restrict__ x,
                                                  float* __restrict__ partial,
                                                  unsigned long long* __restrict__ acc,
                                                  unsigned int* __restrict__ ticket) {
    if (acc != nullptr && blockIdx.x == 0 && threadIdx.x == 0) { *acc = 0ULL; *ticket = 0U; }

    constexpr int rowsPerChunk = N_DIM / CHUNKS_T;
    constexpr int rowsPerWave  = rowsPerChunk / 4;
    constexpr int ITERS        = rowsPerWave / 4;

    const int blk   = blockIdx.x;
    const int b     = blk / CHUNKS_T;
    const int chunk = blk % CHUNKS_T;
    const int wave  = threadIdx.x >> 6;    // 0..3
    const int lane  = threadIdx.x & 63;

    const long long rowStart = (long long)b * N_DIM
                             + (long long)chunk * rowsPerChunk
                             + (long long)wave * rowsPerWave;

    float accv[8];
    #pragma unroll
    for (int k = 0; k < 8; ++k) accv[k] = 0.0f;

    const float* base = x + rowStart * D_DIM + lane * 8;

    fx4 v[2][4][2];

    // prologue: buffer 0 <- rows 0..3
    #pragma unroll
    for (int i = 0; i < 4; ++i) {
        v[0][i][0] = *(const fx4*)(base + i * D_DIM);
        v[0][i][1] = *(const fx4*)(base + i * D_DIM + 4);
    }
    base += 4 * D_DIM;

    #pragma unroll
    for (int it = 0; it < ITERS; ++it) {
        const int cur = it & 1;
        const int nxt = cur ^ 1;

        if (it < ITERS - 1) {   // compile-time branch after full unroll
            #pragma unroll
            for (int i = 0; i < 4; ++i) {
                v[nxt][i][0] = *(const fx4*)(base + i * D_DIM);
                v[nxt][i][1] = *(const fx4*)(base + i * D_DIM + 4);
            }
            base += 4 * D_DIM;
        }

        float ss[4];
        #pragma unroll
        for (int i = 0; i < 4; ++i) {
            ss[i] = v[cur][i][0].x*v[cur][i][0].x + v[cur][i][0].y*v[cur][i][0].y
                  + v[cur][i][0].z*v[cur][i][0].z + v[cur][i][0].w*v[cur][i][0].w
                  + v[cur][i][1].x*v[cur][i][1].x + v[cur][i][1].y*v[cur][i][1].y
                  + v[cur][i][1].z*v[cur][i][1].z + v[cur][i][1].w*v[cur][i][1].w;
        }

        // four interleaved 64-lane butterflies (independent chains)
        #pragma unroll
        for (int off = 1; off < 64; off <<= 1) {
            #pragma unroll
            for (int i = 0; i < 4; ++i) ss[i] += __shfl_xor(ss[i], off);
        }

        #pragma unroll
        for (int i = 0; i < 4; ++i) {
            const float inv = 1.0f / fmaxf(sqrtf(ss[i]), EPS);
            accv[0] += v[cur][i][0].x * inv;
            accv[1] += v[cur][i][0].y * inv;
            accv[2] += v[cur][i][0].z * inv;
            accv[3] += v[cur][i][0].w * inv;
            accv[4] += v[cur][i][1].x * inv;
            accv[5] += v[cur][i][1].y * inv;
            accv[6] += v[cur][i][1].z * inv;
            accv[7] += v[cur][i][1].w * inv;
        }
    }

    // combine the 4 waves' partials deterministically via LDS
    __shared__ float lds[4][D_DIM];
    float* dst = &lds[wave][lane * 8];
    #pragma unroll
    for (int k = 0; k < 8; ++k) dst[k] = accv[k];
    __syncthreads();

    for (int d = threadIdx.x; d < D_DIM; d += 256) {
        float s = lds[0][d] + lds[1][d] + lds[2][d] + lds[3][d];
        partial[(long long)blk * D_DIM + d] = s;
    }
}

// K2: 64 blocks = 8 batches x 8 d-groups (64 d's each), 256 threads.
// Wave q sums chunks c === q (mod 4); LDS-combine, square, 64-lane reduce ->
// block ssq. Fixed-point u64 atomic add (order-independent = deterministic);
// ticket-63 block writes the final scalar.
__global__ __launch_bounds__(256) void k2_batch(const float* __restrict__ partial,
                                                unsigned long long* __restrict__ acc,
                                                unsigned int* __restrict__ ticket,
                                                float* __restrict__ out) {
    const int b  = blockIdx.x >> 3;
    const int g  = blockIdx.x & 7;
    const int dl = threadIdx.x & 63;
    const int q  = threadIdx.x >> 6;
    const int d  = g * 64 + dl;

    float s = 0.0f;
    const float* p = partial + (long long)b * CHUNKS * D_DIM + d;
    for (int c = q; c < CHUNKS; c += 4) s += p[(long long)c * D_DIM];

    __shared__ float lds[4][64];
    lds[q][dl] = s;
    __syncthreads();

    if (q == 0) {
        const float tot = lds[0][dl] + lds[1][dl] + lds[2][dl] + lds[3][dl];
        float v = tot * tot;
        #pragma unroll
        for (int off = 1; off < 64; off <<= 1) v += __shfl_xor(v, off);

        if (dl == 0) {
            const long long q64 = (long long)((double)v * FIX_SCALE);
            atomicAdd(acc, (unsigned long long)q64);
            __threadfence();
            const unsigned int t = atomicAdd(ticket, 1U);
            if (t == (B_DIM * 8 - 1)) {
                const unsigned long long totu = atomicAdd(acc, 0ULL);
                const double tot_d = (double)(long long)totu / FIX_SCALE;
                out[0] = (float)(tot_d / ((double)N_DIM * (double)N_DIM * (double)B_DIM));
            }
        }
    }
}

extern "C" void kernel_launch(void* const* d_in, const int* in_sizes, int n_in,
                              void* d_out, int out_size, void* d_ws, size_t ws_size,
                              hipStream_t stream) {
    const float* x = (const float*)d_in[0];
    float* out = (float*)d_out;

    float* partial = (float*)d_ws;                                  // 8*128*512 floats = 2 MB
    unsigned long long* acc = (unsigned long long*)((char*)d_ws +
                              (size_t)B_DIM * CHUNKS * D_DIM * sizeof(float));
    unsigned int* ticket = (unsigned int*)(acc + 1);
    // dead scratch for the timing probe (after acc/ticket, 16B-aligned)
    float* partial2 = (float*)((char*)(acc + 2) + 0);

    // real pipeline (unchanged from round 7/9)
    k1_partial<CHUNKS><<<dim3(B_DIM * CHUNKS), dim3(256), 0, stream>>>(x, partial, acc, ticket);
    k2_batch<<<dim3(B_DIM * 8), dim3(256), 0, stream>>>(partial, acc, ticket, out);

    // timing probe: identical work at CHUNKS=256 (2048 blocks, 32 waves/CU),
    // result unused. dur_us - 37.25 = this kernel's isolated duration.
    k1_partial<256><<<dim3(B_DIM * 256), dim3(256), 0, stream>>>(x, partial2, nullptr, nullptr);
}

// Round 11
// 32.766 us; speedup vs baseline: 1.8645x; 1.8645x over previous
//
#include <hip/hip_runtime.h>

#define EPS 1e-8f

// Shapes fixed per reference: x [B=8, N=8192, D=512] fp32, scalar fp32 out.
#define B_DIM 8
#define N_DIM 8192
#define D_DIM 512
#define CHUNKS 256   // K1 grid = B*CHUNKS = 2048 blocks (8/CU, 32 waves/CU)
                     // probed in round 10: 23.8 us at this config (L3-warm)
#define FIX_SCALE 1099511627776.0   // 2^40 fixed-point scale for deterministic sum

typedef float fx4 __attribute__((ext_vector_type(4)));

// K1: 256 threads (4 waves). Each wave: 8 rows, 4 rows/iteration, register
// double-buffer (2 iterations, fully unrolled). Lane l owns d-slice [8l,8l+8).
// Block 0 zeroes the K2 accumulator/ticket (stream order guarantees K1 < K2).
__global__ __launch_bounds__(256) void k1_partial(const float* __restrict__ x,
                                                  float* __restrict__ partial,
                                                  unsigned long long* __restrict__ acc,
                                                  unsigned int* __restrict__ ticket) {
    if (blockIdx.x == 0 && threadIdx.x == 0) { *acc = 0ULL; *ticket = 0U; }

    constexpr int rowsPerChunk = N_DIM / CHUNKS;   // 32
    constexpr int rowsPerWave  = rowsPerChunk / 4; // 8
    constexpr int ITERS        = rowsPerWave / 4;  // 2

    const int blk   = blockIdx.x;
    const int b     = blk >> 8;            // / CHUNKS
    const int chunk = blk & (CHUNKS - 1);
    const int wave  = threadIdx.x >> 6;    // 0..3
    const int lane  = threadIdx.x & 63;

    const long long rowStart = (long long)b * N_DIM
                             + (long long)chunk * rowsPerChunk
                             + (long long)wave * rowsPerWave;

    float accv[8];
    #pragma unroll
    for (int k = 0; k < 8; ++k) accv[k] = 0.0f;

    const float* base = x + rowStart * D_DIM + lane * 8;

    fx4 v[2][4][2];

    // prologue: buffer 0 <- rows 0..3
    #pragma unroll
    for (int i = 0; i < 4; ++i) {
        v[0][i][0] = *(const fx4*)(base + i * D_DIM);
        v[0][i][1] = *(const fx4*)(base + i * D_DIM + 4);
    }
    base += 4 * D_DIM;

    #pragma unroll
    for (int it = 0; it < ITERS; ++it) {
        const int cur = it & 1;
        const int nxt = cur ^ 1;

        if (it < ITERS - 1) {   // compile-time branch after full unroll
            #pragma unroll
            for (int i = 0; i < 4; ++i) {
                v[nxt][i][0] = *(const fx4*)(base + i * D_DIM);
                v[nxt][i][1] = *(const fx4*)(base + i * D_DIM + 4);
            }
            base += 4 * D_DIM;
        }

        float ss[4];
        #pragma unroll
        for (int i = 0; i < 4; ++i) {
            ss[i] = v[cur][i][0].x*v[cur][i][0].x + v[cur][i][0].y*v[cur][i][0].y
                  + v[cur][i][0].z*v[cur][i][0].z + v[cur][i][0].w*v[cur][i][0].w
                  + v[cur][i][1].x*v[cur][i][1].x + v[cur][i][1].y*v[cur][i][1].y
                  + v[cur][i][1].z*v[cur][i][1].z + v[cur][i][1].w*v[cur][i][1].w;
        }

        // four interleaved 64-lane butterflies (independent chains)
        #pragma unroll
        for (int off = 1; off < 64; off <<= 1) {
            #pragma unroll
            for (int i = 0; i < 4; ++i) ss[i] += __shfl_xor(ss[i], off);
        }

        #pragma unroll
        for (int i = 0; i < 4; ++i) {
            const float inv = 1.0f / fmaxf(sqrtf(ss[i]), EPS);
            accv[0] += v[cur][i][0].x * inv;
            accv[1] += v[cur][i][0].y * inv;
            accv[2] += v[cur][i][0].z * inv;
            accv[3] += v[cur][i][0].w * inv;
            accv[4] += v[cur][i][1].x * inv;
            accv[5] += v[cur][i][1].y * inv;
            accv[6] += v[cur][i][1].z * inv;
            accv[7] += v[cur][i][1].w * inv;
        }
    }

    // combine the 4 waves' partials deterministically via LDS
    __shared__ float lds[4][D_DIM];
    float* dst = &lds[wave][lane * 8];
    #pragma unroll
    for (int k = 0; k < 8; ++k) dst[k] = accv[k];
    __syncthreads();

    for (int d = threadIdx.x; d < D_DIM; d += 256) {
        float s = lds[0][d] + lds[1][d] + lds[2][d] + lds[3][d];
        partial[(long long)blk * D_DIM + d] = s;
    }
}

// K2: 64 blocks = 8 batches x 8 d-groups (64 d's each), 512 threads (8 waves).
// Wave q sums chunks c === q (mod 8) with 4 independent accumulators (keeps
// 4 loads in flight, breaks the serial load-add chain). LDS-combine the 8
// waves, square, 64-lane reduce -> block ssq. Fixed-point u64 atomic add
// (order-independent = deterministic); ticket-63 block writes the scalar.
__global__ __launch_bounds__(512) void k2_batch(const float* __restrict__ partial,
                                                unsigned long long* __restrict__ acc,
                                                unsigned int* __restrict__ ticket,
                                                float* __restrict__ out) {
    const int b  = blockIdx.x >> 3;
    const int g  = blockIdx.x & 7;
    const int dl = threadIdx.x & 63;
    const int q  = threadIdx.x >> 6;   // 0..7
    const int d  = g * 64 + dl;

    const float* p = partial + (long long)b * CHUNKS * D_DIM + d;

    // c = q, q+8, ..., 32 values; 4 independent chains
    float s0 = 0.0f, s1 = 0.0f, s2 = 0.0f, s3 = 0.0f;
    #pragma unroll
    for (int c = 0; c < CHUNKS / 8; c += 4) {
        s0 += p[(long long)(q + (c + 0) * 8) * D_DIM];
        s1 += p[(long long)(q + (c + 1) * 8) * D_DIM];
        s2 += p[(long long)(q + (c + 2) * 8) * D_DIM];
        s3 += p[(long long)(q + (c + 3) * 8) * D_DIM];
    }
    const float s = (s0 + s1) + (s2 + s3);

    __shared__ float lds[8][64];
    lds[q][dl] = s;
    __syncthreads();

    if (q == 0) {
        float tot = 0.0f;
        #pragma unroll
        for (int w = 0; w < 8; ++w) tot += lds[w][dl];
        float v = tot * tot;
        #pragma unroll
        for (int off = 1; off < 64; off <<= 1) v += __shfl_xor(v, off);

        if (dl == 0) {
            const long long q64 = (long long)((double)v * FIX_SCALE);
            atomicAdd(acc, (unsigned long long)q64);
            __threadfence();
            const unsigned int t = atomicAdd(ticket, 1U);
            if (t == (B_DIM * 8 - 1)) {
                const unsigned long long totu = atomicAdd(acc, 0ULL);
                const double tot_d = (double)(long long)totu / FIX_SCALE;
                out[0] = (float)(tot_d / ((double)N_DIM * (double)N_DIM * (double)B_DIM));
            }
        }
    }
}

extern "C" void kernel_launch(void* const* d_in, const int* in_sizes, int n_in,
                              void* d_out, int out_size, void* d_ws, size_t ws_size,
                              hipStream_t stream) {
    const float* x = (const float*)d_in[0];
    float* out = (float*)d_out;

    float* partial = (float*)d_ws;                                  // 8*256*512 floats = 4 MB
    unsigned long long* acc = (unsigned long long*)((char*)d_ws +
                              (size_t)B_DIM * CHUNKS * D_DIM * sizeof(float));
    unsigned int* ticket = (unsigned int*)(acc + 1);

    k1_partial<<<dim3(B_DIM * CHUNKS), dim3(256), 0, stream>>>(x, partial, acc, ticket);
    k2_batch<<<dim3(B_DIM * 8), dim3(512), 0, stream>>>(partial, acc, ticket, out);
}